// Round 9
// baseline (304.079 us; speedup 1.0000x reference)
//
#include <hip/hip_runtime.h>
#include <math.h>

#define B_ 4
#define S_ 2048
#define H_ 16
#define D_ 64
#define C_ 128
#define NC_ 16          // chunks per sequence
#define BH_ 64          // B*H sequences

// ---------------------------------------------------------------------------
// Kernel A: hierarchical KV scan. Block = (bh, cg); scans its 4 chunks
// serially. Writes LOCAL-exclusive prefix states into kvbuf[bh][c] for
// c%4!=0, and the group's 4-chunk TOTAL into the group-leading slot
// kvbuf[bh][cg*4] (whose local-exclusive prefix is identically zero).
// No extra scratch, no d_out aliasing (round-8 race fixed).
// ---------------------------------------------------------------------------
__global__ __launch_bounds__(256) void scan4_kernel(
    const float* __restrict__ qk, const float* __restrict__ v,
    float* __restrict__ kvbuf)
{
  __shared__ float Kl[C_][D_];   // 32 KB
  __shared__ float Vl[C_][D_];   // 32 KB
  const int bid = blockIdx.x;
  const int bh = bid >> 2, cg = bid & 3;
  const int b = bh >> 4, h = bh & 15;
  const int tid = threadIdx.x;
  const int dkt = tid >> 4, dvt = tid & 15;

  const size_t kbase = (((size_t)b * S_ * 2 + 1) * H_ + h) * D_;
  const size_t vbase = ((size_t)b * S_ * H_ + h) * D_;

  float run[4][4] = {};

  for (int i = 0; i < 4; ++i) {
    const int c = cg * 4 + i;
    const int t0 = c * C_;
    __syncthreads();                       // Kl/Vl reuse guard
    #pragma unroll
    for (int u = 0; u < 8; ++u) {
      int f = tid + u * 256;
      int row = f >> 4, c4 = (f & 15) << 2;
      size_t t = (size_t)t0 + row;
      *reinterpret_cast<float4*>(&Kl[row][c4]) =
          *reinterpret_cast<const float4*>(qk + kbase + t * (2*H_*D_) + c4);
      *reinterpret_cast<float4*>(&Vl[row][c4]) =
          *reinterpret_cast<const float4*>(v + vbase + t * (H_*D_) + c4);
    }
    // local-EXCLUSIVE prefix: write run BEFORE accumulating this chunk
    // (for i==0 this writes zeros; overwritten by the group total below)
    if (i > 0) {
      float* op = kvbuf + ((size_t)bh * NC_ + c) * (D_*D_);
      #pragma unroll
      for (int a = 0; a < 4; ++a)
        *reinterpret_cast<float4*>(op + (dkt*4+a)*D_ + dvt*4) =
            make_float4(run[a][0], run[a][1], run[a][2], run[a][3]);
    }
    __syncthreads();
    #pragma unroll 4
    for (int s = 0; s < C_; ++s) {
      float4 k4 = *reinterpret_cast<const float4*>(&Kl[s][dkt*4]);
      float4 v4 = *reinterpret_cast<const float4*>(&Vl[s][dvt*4]);
      float kk[4] = {k4.x, k4.y, k4.z, k4.w};
      float vv[4] = {v4.x, v4.y, v4.z, v4.w};
      #pragma unroll
      for (int a = 0; a < 4; ++a)
        #pragma unroll
        for (int e = 0; e < 4; ++e)
          run[a][e] += kk[a] * vv[e];
    }
  }
  // group total -> group-leading chunk slot (its local prefix is zero)
  float* tp = kvbuf + ((size_t)bh * NC_ + cg * 4) * (D_*D_);
  #pragma unroll
  for (int a = 0; a < 4; ++a)
    *reinterpret_cast<float4*>(tp + (dkt*4+a)*D_ + dvt*4) =
        make_float4(run[a][0], run[a][1], run[a][2], run[a][3]);
}

// ---------------------------------------------------------------------------
// Kernel B: output. 512 threads, 2 blocks/CU (80 KB LDS) = 16 waves/CU.
// Thread = (TG=tid>>4 in 0..31, SG=tid&15). TG owns rows {2TG,2TG+1} (low
// half) and {64+2TG,65+2TG} (high half) -> both causal windows keep every
// wave busy. Phase A: M = (c%4 ? local_excl[c] : 0) + sum_{g<c/4} total[4g].
// ---------------------------------------------------------------------------
__global__ __launch_bounds__(512, 4) void out_kernel(
    const float* __restrict__ qk, const float* __restrict__ v,
    const float* __restrict__ nrm, const float* __restrict__ kvbuf,
    float* __restrict__ outp)
{
  __shared__ float Qt2[32][D_][4];   // 32 KB  [TG][d ^ (TG&7)][slot]
  __shared__ float Kt[D_][64];       // 16 KB  [d][s-in-window]
  __shared__ float Sc[C_][64];       // 32 KB  [row][4*(sq ^ key)]

  const int bid = blockIdx.x;
  const int bh = bid / NC_, c = bid % NC_;
  const int b = bh >> 4, h = bh & 15;
  const int t0 = c * C_;
  const int tid = threadIdx.x;
  const int TG = tid >> 4, SG = tid & 15;
  const int key = TG & 7;

  // ---- stage Q (swizzled, slot-mapped) ----
  {
    const int row = tid >> 2;              // 0..127
    const int d0 = (tid & 3) * 16;
    const int otg  = (row < 64) ? (row >> 1) : ((row - 64) >> 1);
    const int slot = (row < 64) ? (row & 1) : (2 + (row & 1));
    const int okey = otg & 7;
    const float* qrow =
        qk + ((((size_t)(b * S_ + t0 + row)) * 2 + 0) * H_ + h) * D_ + d0;
    float tmp[16];
    #pragma unroll
    for (int u = 0; u < 4; ++u) {
      float4 x = *reinterpret_cast<const float4*>(qrow + u * 4);
      tmp[u*4+0] = x.x; tmp[u*4+1] = x.y; tmp[u*4+2] = x.z; tmp[u*4+3] = x.w;
    }
    #pragma unroll
    for (int u = 0; u < 16; ++u)
      Qt2[otg][(d0 + u) ^ okey][slot] = tmp[u];
  }
  __syncthreads();

  float o[4][4] = {};

  // ---- phase A: o += q . M_prefix ----
  if (c > 0) {
    const int ng = c >> 2;                 // # group totals (block-uniform)
    const bool has_local = (c & 3) != 0;
    const float* M0 = kvbuf + ((size_t)bh * NC_ + c) * (D_*D_);
    const float* T0 = kvbuf + ((size_t)bh * NC_) * (D_*D_);  // slots 0,4,8,12
    #pragma unroll 4
    for (int dk = 0; dk < D_; ++dk) {
      float4 m4 = make_float4(0.f, 0.f, 0.f, 0.f);
      if (has_local)
        m4 = *reinterpret_cast<const float4*>(M0 + dk * D_ + SG * 4);
      for (int g = 0; g < ng; ++g) {
        float4 t4 = *reinterpret_cast<const float4*>(
            T0 + (size_t)(4 * g) * (D_*D_) + dk * D_ + SG * 4);
        m4.x += t4.x; m4.y += t4.y; m4.z += t4.z; m4.w += t4.w;
      }
      float4 qq = *reinterpret_cast<const float4*>(&Qt2[TG][dk ^ key][0]);
      float qv[4] = {qq.x, qq.y, qq.z, qq.w};
      float mv[4] = {m4.x, m4.y, m4.z, m4.w};
      #pragma unroll
      for (int sl = 0; sl < 4; ++sl)
        #pragma unroll
        for (int jj = 0; jj < 4; ++jj)
          o[sl][jj] += qv[sl] * mv[jj];
    }
  }

  // ---- phase B: two 64-wide causal s-windows ----
  const float* kbase2 = qk + (((size_t)b * S_ * 2 + 1) * H_ + h) * D_;
  const float* vbase2 = v + ((size_t)b * S_ * H_ + h) * D_;
  const int rown[4] = {TG*2, TG*2+1, 64+TG*2, 65+TG*2};

  #pragma unroll
  for (int j = 0; j < 2; ++j) {
    const int sbase = j * 64;
    __syncthreads();                       // Kt/Sc reuse guard
    { // stage Kt (transposed): conflict-free (sl distinct per lane)
      const int sl = tid & 63;
      const int d0 = (tid >> 6) * 8;
      const float* krow = kbase2 + (size_t)(t0 + sbase + sl) * (2*H_*D_) + d0;
      float4 ka = *reinterpret_cast<const float4*>(krow);
      float4 kb = *reinterpret_cast<const float4*>(krow + 4);
      Kt[d0+0][sl] = ka.x; Kt[d0+1][sl] = ka.y;
      Kt[d0+2][sl] = ka.z; Kt[d0+3][sl] = ka.w;
      Kt[d0+4][sl] = kb.x; Kt[d0+5][sl] = kb.y;
      Kt[d0+6][sl] = kb.z; Kt[d0+7][sl] = kb.w;
    }
    __syncthreads();

    // scores: window 0 -> all 4 slots; window 1 -> slots 2,3 only
    const int slo = (j == 0) ? 0 : 2;
    float sc[4][4] = {};
    #pragma unroll 4
    for (int d = 0; d < D_; ++d) {
      float4 qq = *reinterpret_cast<const float4*>(&Qt2[TG][d ^ key][0]);
      float4 k4 = *reinterpret_cast<const float4*>(&Kt[d][SG * 4]);
      float qv[4] = {qq.x, qq.y, qq.z, qq.w};
      float kv[4] = {k4.x, k4.y, k4.z, k4.w};
      #pragma unroll
      for (int sl = 0; sl < 4; ++sl) {
        if (sl < slo) continue;
        #pragma unroll
        for (int jj = 0; jj < 4; ++jj)
          sc[sl][jj] += qv[sl] * kv[jj];
      }
    }
    #pragma unroll
    for (int sl = 0; sl < 4; ++sl) {       // mask + swizzled store
      if (sl < slo) continue;
      const int r = rown[sl];
      float4 w;
      w.x = (sbase + SG*4 + 0 <= r) ? sc[sl][0] : 0.f;
      w.y = (sbase + SG*4 + 1 <= r) ? sc[sl][1] : 0.f;
      w.z = (sbase + SG*4 + 2 <= r) ? sc[sl][2] : 0.f;
      w.w = (sbase + SG*4 + 3 <= r) ? sc[sl][3] : 0.f;
      *reinterpret_cast<float4*>(&Sc[r][4 * (SG ^ key)]) = w;
    }
    __syncthreads();

    // PV: V rows from global (L1-broadcast across wave), Sc broadcast reads
    #pragma unroll 2
    for (int sq = 0; sq < 16; ++sq) {
      const size_t sg0 = (size_t)t0 + sbase + sq * 4;
      float4 v0 = *reinterpret_cast<const float4*>(vbase2 + (sg0+0)*(H_*D_) + SG*4);
      float4 v1 = *reinterpret_cast<const float4*>(vbase2 + (sg0+1)*(H_*D_) + SG*4);
      float4 v2 = *reinterpret_cast<const float4*>(vbase2 + (sg0+2)*(H_*D_) + SG*4);
      float4 v3 = *reinterpret_cast<const float4*>(vbase2 + (sg0+3)*(H_*D_) + SG*4);
      const int scol = 4 * (sq ^ key);
      #pragma unroll
      for (int sl = 0; sl < 4; ++sl) {
        if (sl < slo) continue;
        float4 s4 = *reinterpret_cast<const float4*>(&Sc[rown[sl]][scol]);
        o[sl][0] += s4.x*v0.x + s4.y*v1.x + s4.z*v2.x + s4.w*v3.x;
        o[sl][1] += s4.x*v0.y + s4.y*v1.y + s4.z*v2.y + s4.w*v3.y;
        o[sl][2] += s4.x*v0.z + s4.y*v1.z + s4.z*v2.z + s4.w*v3.z;
        o[sl][3] += s4.x*v0.w + s4.y*v1.w + s4.z*v2.w + s4.w*v3.w;
      }
    }
  }

  // ---- epilogue ----
  #pragma unroll
  for (int sl = 0; sl < 4; ++sl) {
    const size_t t = (size_t)t0 + rown[sl];
    float nv = nrm[((size_t)(b * S_) + t) * H_ + h];
    float inv = expf(-nv);
    float4 ov = make_float4(o[sl][0]*inv, o[sl][1]*inv,
                            o[sl][2]*inv, o[sl][3]*inv);
    *reinterpret_cast<float4*>(
        outp + (((size_t)(b * S_) + t) * H_ + h) * D_ + SG * 4) = ov;
  }
}

extern "C" void kernel_launch(void* const* d_in, const int* in_sizes, int n_in,
                              void* d_out, int out_size, void* d_ws, size_t ws_size,
                              hipStream_t stream) {
  const float* qk  = (const float*)d_in[0];   // (B,S,2,H,D) f32
  const float* v   = (const float*)d_in[1];   // (B,S,H,D)   f32
  const float* nrm = (const float*)d_in[2];   // (B,S,H)     f32
  float* out = (float*)d_out;                 // (B,S,H,D)   f32
  float* kvbuf = (float*)d_ws;                // 64*16*4096 f32 = 16.8 MB

  scan4_kernel<<<dim3(BH_ * 4), dim3(256), 0, stream>>>(qk, v, kvbuf);
  out_kernel<<<dim3(BH_ * NC_), dim3(512), 0, stream>>>(qk, v, nrm, kvbuf, out);
}

// Round 11
// 271.731 us; speedup vs baseline: 1.1190x; 1.1190x over previous
//
#include <hip/hip_runtime.h>
#include <math.h>

#define B_ 4
#define S_ 2048
#define H_ 16
#define D_ 64
#define C_ 128
#define NC_ 16          // chunks per sequence
#define BH_ 64          // B*H sequences

// ---------------------------------------------------------------------------
// Kernel 1: scan2. Block (bh,g) scans chunks {2g, 2g+1} serially.
// Writes local-exclusive prefix (=KV of chunk 2g) into slot[2g+1] and the
// 2-chunk group TOTAL into slot[2g]. 64 KB LDS -> 2 blocks/CU.
// ---------------------------------------------------------------------------
__global__ __launch_bounds__(256) void scan2_kernel(
    const float* __restrict__ qk, const float* __restrict__ v,
    float* __restrict__ kvbuf)
{
  __shared__ float Kl[C_][D_];   // 32 KB
  __shared__ float Vl[C_][D_];   // 32 KB
  const int bid = blockIdx.x;
  const int bh = bid >> 3, g = bid & 7;
  const int b = bh >> 4, h = bh & 15;
  const int tid = threadIdx.x;
  const int dkt = tid >> 4, dvt = tid & 15;

  const size_t kbase = (((size_t)b * S_ * 2 + 1) * H_ + h) * D_;
  const size_t vbase = ((size_t)b * S_ * H_ + h) * D_;

  float run[4][4] = {};

  for (int i = 0; i < 2; ++i) {
    const int c = g * 2 + i;
    const int t0 = c * C_;
    __syncthreads();                       // Kl/Vl reuse guard
    #pragma unroll
    for (int u = 0; u < 8; ++u) {
      int f = tid + u * 256;
      int row = f >> 4, c4 = (f & 15) << 2;
      size_t t = (size_t)t0 + row;
      *reinterpret_cast<float4*>(&Kl[row][c4]) =
          *reinterpret_cast<const float4*>(qk + kbase + t * (2*H_*D_) + c4);
      *reinterpret_cast<float4*>(&Vl[row][c4]) =
          *reinterpret_cast<const float4*>(v + vbase + t * (H_*D_) + c4);
    }
    if (i == 1) {   // local-exclusive prefix for the odd chunk
      float* op = kvbuf + ((size_t)(bh * NC_ + c)) * (D_*D_);
      #pragma unroll
      for (int a = 0; a < 4; ++a)
        *reinterpret_cast<float4*>(op + (dkt*4+a)*D_ + dvt*4) =
            make_float4(run[a][0], run[a][1], run[a][2], run[a][3]);
    }
    __syncthreads();
    #pragma unroll 4
    for (int s = 0; s < C_; ++s) {
      float4 k4 = *reinterpret_cast<const float4*>(&Kl[s][dkt*4]);
      float4 v4 = *reinterpret_cast<const float4*>(&Vl[s][dvt*4]);
      float kk[4] = {k4.x, k4.y, k4.z, k4.w};
      float vv[4] = {v4.x, v4.y, v4.z, v4.w};
      #pragma unroll
      for (int a = 0; a < 4; ++a)
        #pragma unroll
        for (int e = 0; e < 4; ++e)
          run[a][e] += kk[a] * vv[e];
    }
  }
  float* tp = kvbuf + ((size_t)(bh * NC_ + g * 2)) * (D_*D_);
  #pragma unroll
  for (int a = 0; a < 4; ++a)
    *reinterpret_cast<float4*>(tp + (dkt*4+a)*D_ + dvt*4) =
        make_float4(run[a][0], run[a][1], run[a][2], run[a][3]);
}

// ---------------------------------------------------------------------------
// Kernel 2: in-place EXCLUSIVE prefix over the 8 even (group-total) slots.
// grid = BH_*4 blocks; each owns 1024 floats of the 4096.
// ---------------------------------------------------------------------------
__global__ __launch_bounds__(256) void gprefix_kernel(float* __restrict__ kvbuf)
{
  const int bid = blockIdx.x;
  const int bh = bid >> 2, part = bid & 3;
  const size_t off = (size_t)part * 1024 + (size_t)threadIdx.x * 4;
  float4 run = make_float4(0.f, 0.f, 0.f, 0.f);
  for (int g = 0; g < 8; ++g) {
    float* p = kvbuf + ((size_t)(bh * NC_ + 2 * g)) * (D_*D_) + off;
    float4 t = *reinterpret_cast<float4*>(p);
    *reinterpret_cast<float4*>(p) = run;
    run.x += t.x; run.y += t.y; run.z += t.z; run.w += t.w;
  }
}

// ---------------------------------------------------------------------------
// Kernel 3: output over 64-row tiles. grid = BH_*NC_*2, 256 threads,
// LDS 48 KB -> 3 blocks/CU (12 waves). TG=tid>>4 owns 4 rows, SG=tid&15.
// half0: causal window only. half1: dense window + causal window.
// M_prefix = slot[c&~1] (group-excl) + (c odd ? slot[c] : 0).
// ---------------------------------------------------------------------------
__global__ __launch_bounds__(256) void out_kernel(
    const float* __restrict__ qk, const float* __restrict__ v,
    const float* __restrict__ nrm, const float* __restrict__ kvbuf,
    float* __restrict__ outp)
{
  __shared__ float Qt[16][D_][4];   // 16 KB [otg][d ^ (otg&7)][slot]
  __shared__ float Kt[D_][64];      // 16 KB [d][s-in-window]
  __shared__ float Sc[64][64];      // 16 KB [row_l][4*(sq ^ key)]

  const int bid = blockIdx.x;
  const int bh = bid >> 5, r5 = bid & 31;
  const int c = r5 >> 1, half = r5 & 1;
  const int b = bh >> 4, h = bh & 15;
  const int R0 = c * C_ + half * 64;       // global row base of this tile
  const int tid = threadIdx.x;
  const int TG = tid >> 4, SG = tid & 15;
  const int tb = TG * 4;
  const int key = TG & 7;

  // ---- stage Q rows R0..R0+63 (swizzled) ----
  {
    const int row = tid >> 2;              // 0..63
    const int d0 = (tid & 3) * 16;
    const int otg = row >> 2, slot = row & 3, okey = otg & 7;
    const float* qrow =
        qk + ((((size_t)(b * S_ + R0 + row)) * 2 + 0) * H_ + h) * D_ + d0;
    float tmp[16];
    #pragma unroll
    for (int u = 0; u < 4; ++u) {
      float4 x = *reinterpret_cast<const float4*>(qrow + u * 4);
      tmp[u*4+0] = x.x; tmp[u*4+1] = x.y; tmp[u*4+2] = x.z; tmp[u*4+3] = x.w;
    }
    #pragma unroll
    for (int u = 0; u < 16; ++u)
      Qt[otg][(d0 + u) ^ okey][slot] = tmp[u];
  }
  __syncthreads();

  float o[4][4] = {};

  // ---- phase A: o += q . M_prefix (2 coalesced global reads per dk) ----
  if (c > 0) {
    const float* gp = kvbuf + ((size_t)(bh * NC_ + (c & ~1))) * (D_*D_);
    const float* lp = kvbuf + ((size_t)(bh * NC_ + c)) * (D_*D_);
    const bool odd = (c & 1) != 0;
    #pragma unroll 4
    for (int dk = 0; dk < D_; ++dk) {
      float4 m4 = *reinterpret_cast<const float4*>(gp + dk * D_ + SG * 4);
      if (odd) {
        float4 l4 = *reinterpret_cast<const float4*>(lp + dk * D_ + SG * 4);
        m4.x += l4.x; m4.y += l4.y; m4.z += l4.z; m4.w += l4.w;
      }
      float4 qq = *reinterpret_cast<const float4*>(&Qt[TG][dk ^ key][0]);
      float qv[4] = {qq.x, qq.y, qq.z, qq.w};
      float mv[4] = {m4.x, m4.y, m4.z, m4.w};
      #pragma unroll
      for (int sl = 0; sl < 4; ++sl)
        #pragma unroll
        for (int jj = 0; jj < 4; ++jj)
          o[sl][jj] += qv[sl] * mv[jj];
    }
  }

  // ---- phase B: windows (half1: dense then causal; half0: causal only) ----
  const float* kbase2 = qk + (((size_t)b * S_ * 2 + 1) * H_ + h) * D_;
  const float* vbase2 = v + ((size_t)b * S_ * H_ + h) * D_;
  const int nw = 1 + half;

  for (int w = 0; w < nw; ++w) {
    const int sW = c * C_ + w * 64;        // window global s-base
    const bool causal = (w == nw - 1);     // last window sits on the diagonal
    __syncthreads();                       // Kt/Sc reuse guard
    { // stage Kt (transposed): wave-stride-1 writes, conflict-free
      const int sl = tid & 63;
      const int d0b = (tid >> 6) * 16;
      const float* krow = kbase2 + (size_t)(sW + sl) * (2*H_*D_) + d0b;
      #pragma unroll
      for (int u = 0; u < 4; ++u) {
        float4 kx = *reinterpret_cast<const float4*>(krow + u * 4);
        Kt[d0b + u*4 + 0][sl] = kx.x;
        Kt[d0b + u*4 + 1][sl] = kx.y;
        Kt[d0b + u*4 + 2][sl] = kx.z;
        Kt[d0b + u*4 + 3][sl] = kx.w;
      }
    }
    __syncthreads();

    // scores for quad SG over this thread's 4 rows (skip fully-masked quads)
    if (!causal || SG * 4 <= tb + 3) {
      float sc[4][4] = {};
      #pragma unroll 4
      for (int d = 0; d < D_; ++d) {
        float4 qq = *reinterpret_cast<const float4*>(&Qt[TG][d ^ key][0]);
        float4 k4 = *reinterpret_cast<const float4*>(&Kt[d][SG * 4]);
        float qv[4] = {qq.x, qq.y, qq.z, qq.w};
        float kv[4] = {k4.x, k4.y, k4.z, k4.w};
        #pragma unroll
        for (int sl = 0; sl < 4; ++sl)
          #pragma unroll
          for (int jj = 0; jj < 4; ++jj)
            sc[sl][jj] += qv[sl] * kv[jj];
      }
      #pragma unroll
      for (int sl = 0; sl < 4; ++sl) {
        const int rl = tb + sl;            // tile-local row == window-local s
        float4 wv;
        if (causal) {
          wv.x = (SG*4 + 0 <= rl) ? sc[sl][0] : 0.f;
          wv.y = (SG*4 + 1 <= rl) ? sc[sl][1] : 0.f;
          wv.z = (SG*4 + 2 <= rl) ? sc[sl][2] : 0.f;
          wv.w = (SG*4 + 3 <= rl) ? sc[sl][3] : 0.f;
        } else {
          wv = make_float4(sc[sl][0], sc[sl][1], sc[sl][2], sc[sl][3]);
        }
        *reinterpret_cast<float4*>(&Sc[rl][4 * (SG ^ key)]) = wv;
      }
    }
    __syncthreads();

    // PV: V rows from global (L1-broadcast), Sc swizzled reads.
    #pragma unroll 2
    for (int sq = 0; sq < 16; ++sq) {
      if (causal && sq * 4 > tb + 3) break;   // matches written-quad set
      const size_t sg0 = (size_t)sW + sq * 4;
      float4 v0 = *reinterpret_cast<const float4*>(vbase2 + (sg0+0)*(H_*D_) + SG*4);
      float4 v1 = *reinterpret_cast<const float4*>(vbase2 + (sg0+1)*(H_*D_) + SG*4);
      float4 v2 = *reinterpret_cast<const float4*>(vbase2 + (sg0+2)*(H_*D_) + SG*4);
      float4 v3 = *reinterpret_cast<const float4*>(vbase2 + (sg0+3)*(H_*D_) + SG*4);
      const int scol = 4 * (sq ^ key);
      #pragma unroll
      for (int sl = 0; sl < 4; ++sl) {
        float4 s4 = *reinterpret_cast<const float4*>(&Sc[tb + sl][scol]);
        o[sl][0] += s4.x*v0.x + s4.y*v1.x + s4.z*v2.x + s4.w*v3.x;
        o[sl][1] += s4.x*v0.y + s4.y*v1.y + s4.z*v2.y + s4.w*v3.y;
        o[sl][2] += s4.x*v0.z + s4.y*v1.z + s4.z*v2.z + s4.w*v3.z;
        o[sl][3] += s4.x*v0.w + s4.y*v1.w + s4.z*v2.w + s4.w*v3.w;
      }
    }
  }

  // ---- epilogue ----
  #pragma unroll
  for (int sl = 0; sl < 4; ++sl) {
    const size_t t = (size_t)R0 + tb + sl;
    float nv = nrm[((size_t)b * S_ + t) * H_ + h];
    float inv = expf(-nv);
    float4 ov = make_float4(o[sl][0]*inv, o[sl][1]*inv,
                            o[sl][2]*inv, o[sl][3]*inv);
    *reinterpret_cast<float4*>(
        outp + (((size_t)b * S_ + t) * H_ + h) * D_ + SG * 4) = ov;
  }
}

extern "C" void kernel_launch(void* const* d_in, const int* in_sizes, int n_in,
                              void* d_out, int out_size, void* d_ws, size_t ws_size,
                              hipStream_t stream) {
  const float* qk  = (const float*)d_in[0];   // (B,S,2,H,D) f32
  const float* v   = (const float*)d_in[1];   // (B,S,H,D)   f32
  const float* nrm = (const float*)d_in[2];   // (B,S,H)     f32
  float* out = (float*)d_out;                 // (B,S,H,D)   f32
  float* kvbuf = (float*)d_ws;                // 64*16*4096 f32 = 16.8 MB

  scan2_kernel<<<dim3(BH_ * 8), dim3(256), 0, stream>>>(qk, v, kvbuf);
  gprefix_kernel<<<dim3(BH_ * 4), dim3(256), 0, stream>>>(kvbuf);
  out_kernel<<<dim3(BH_ * NC_ * 2), dim3(256), 0, stream>>>(qk, v, nrm, kvbuf, out);
}